// Round 8
// baseline (82.640 us; speedup 1.0000x reference)
//
#include <hip/hip_runtime.h>
#include <hip/hip_bf16.h>

typedef __attribute__((ext_vector_type(8))) short bf16x8;
typedef __attribute__((ext_vector_type(4))) float f32x4;

static __device__ __forceinline__ unsigned short f2bf(float f) {
    unsigned int u = __float_as_uint(f);
    unsigned int rnd = 0x7FFFu + ((u >> 16) & 1u);
    return (unsigned short)((u + rnd) >> 16);
}

// pack two f32 -> 2xbf16 (RNE) using v_cvt_pk_bf16_f32
static __device__ __forceinline__ bf16x8 cvt8(float4 u, float4 v) {
    union { bf16x8 r; __hip_bfloat162 h[4]; } o;
    o.h[0] = __float22bfloat162_rn(float2{u.x, u.y});
    o.h[1] = __float22bfloat162_rn(float2{u.z, u.w});
    o.h[2] = __float22bfloat162_rn(float2{v.x, v.y});
    o.h[3] = __float22bfloat162_rn(float2{v.z, v.w});
    return o.r;
}

// async global->LDS DMA, 16B per lane, wave-uniform LDS base + lane*16
typedef __attribute__((address_space(1))) const unsigned int guint;
typedef __attribute__((address_space(3))) unsigned int luint;
static __device__ __forceinline__ void gload_lds16(const float* g, float* l) {
    __builtin_amdgcn_global_load_lds((guint*)g, (luint*)l, 16, 0, 0);
}

// ---------------- Kernel 1: hypernetwork hw = hyper@W1+b1, bias = hyper@Wb+bb
__global__ __launch_bounds__(256)
void hypernet_kernel(const float* __restrict__ hyper,   // (8,256)
                     const float* __restrict__ W1,      // (256,4096)
                     const float* __restrict__ b1,      // (4096)
                     const float* __restrict__ Wb,      // (256,64)
                     const float* __restrict__ bb,      // (64)
                     float* __restrict__ hw,            // ws: 8*4096
                     float* __restrict__ bias)          // ws: 8*64
{
    __shared__ float red[256];
    const int tid = threadIdx.x;
    const int p   = tid >> 5;          // 0..7  (d-range)
    const int jj  = tid & 31;          // 0..31 (output within block)
    const int o0  = blockIdx.x * 32;
    const int o   = o0 + jj;

    float acc = 0.f;
    if (o0 < 8 * 4096) {               // hw part (uniform per block)
        int h = o >> 12, j = o & 4095;
        const float* hr = hyper + (h << 8);
        #pragma unroll
        for (int i = 0; i < 32; ++i) {
            int d = (p << 5) + i;
            acc += hr[d] * W1[d * 4096 + j];
        }
    } else {                           // bias part
        int t = o - 8 * 4096;          // 0..511
        int h = t >> 6, s = t & 63;
        const float* hr = hyper + (h << 8);
        #pragma unroll
        for (int i = 0; i < 32; ++i) {
            int d = (p << 5) + i;
            acc += hr[d] * Wb[d * 64 + s];
        }
    }
    red[tid] = acc;
    __syncthreads();
    if (p == 0) {
        float sum = red[jj]       + red[32 + jj]  + red[64 + jj]  + red[96 + jj]
                  + red[128 + jj] + red[160 + jj] + red[192 + jj] + red[224 + jj];
        if (o0 < 8 * 4096) hw[o] = sum + b1[o & 4095];
        else {
            int t = o - 8 * 4096;
            bias[t] = sum + bb[t & 63];
        }
    }
}

// ---------------- Kernel 2: W[h] = down@up, packed directly into MFMA
// B-fragment order for v_mfma_f32_16x16x32_bf16 (validated in round 1).
// 64-thread blocks -> 512 blocks (2/CU) instead of 128 (0.5/CU).
__global__ void pack_kernel(const float* __restrict__ hw,          // 8*4096
                            unsigned short* __restrict__ packed)   // 32768 bf16
{
    int p = blockIdx.x * blockDim.x + threadIdx.x;  // 0..32767
    int b   = p & 7;
    int l   = (p >> 3) & 63;
    int kap = (p >> 9) & 1;
    int n   = p >> 10;                              // 0..31
    int k   = kap * 32 + ((l >> 4) << 3) + b;       // 0..63 (= target feature d)
    int col = (n << 4) + (l & 15);                  // 0..511
    int h = col >> 6, s = col & 63;
    const float* hwh = hw + h * 4096;
    float acc = 0.f;
    #pragma unroll
    for (int r = 0; r < 32; ++r)
        acc += hwh[k * 32 + r] * hwh[2048 + r * 64 + s];
    packed[p] = f2bf(acc);
}

// ---------------- Kernel 3: main — LDS-staged streaming GEMM, single
// residency round: 1024 blocks = EXACTLY 4 blocks/CU at (256,4); register
// diet (~120 unified) via global_load_lds staging (zero staging VGPRs):
// pre-swizzled GLOBAL source + linear LDS dest + swizzled read (rule #21;
// read-side XOR identical to validated round 7). DMA for group g+1 issued at
// group-g start -> full group compute hides L3 latency, no reg round-trip.
// h-split acc; bias as MFMA C-init; masks reg->LDS stride-12 (2-way, free).
#define GR 32

__global__ __launch_bounds__(256, 4)
void main_kernel(const float* __restrict__ X,       // (M,64)
                 const float* __restrict__ Mask,    // (M,8)
                 const unsigned short* __restrict__ packedB,
                 const float* __restrict__ bias,    // (8,64)
                 float* __restrict__ Out,           // (M,64)
                 int M)
{
    __shared__ __align__(16) float sX[2][GR * 64];  // 16 KB, LINEAR (DMA dest)
    __shared__ __align__(16) float sM[2][GR * 12];  // 3 KB, stride-12 padded

    const int tid  = threadIdx.x;
    const int lane = tid & 63;
    const int w    = tid >> 6;          // wave id -> output col tile
    const int c    = lane & 15;         // A row-within-tile / D col-within-tile
    const int g    = lane >> 4;         // k-group / D row-group
    const int s    = (w << 4) + c;      // output column 0..63

    const int blockRow = blockIdx.x * (4 * GR);     // 128 rows/block

    // staging map: LDS quad slot tid (and tid+256) is LINEAR; its content is
    // the PRE-SWIZZLED global quad: row = slot>>4, q = slot&15,
    // src quad = q ^ ((row&7)<<1). (row+16)&7 == row&7 -> second chunk = +1024.
    const int row0 = tid >> 4, q0 = tid & 15;
    const int gsw0 = row0 * 64 + ((q0 ^ ((row0 & 7) << 1)) << 2);  // word off
    const int smw  = (tid >> 3) * 12 + (tid & 7);   // mask LDS word (2-way)
    float* ldst0 = &sX[0][tid << 2];
    float* ldst1 = &sX[1][tid << 2];

    // ---- issue group-0 staging DMA + mask load
    {
        const float* xb = X + blockRow * 64;
        gload_lds16(xb + gsw0, ldst0);
        gload_lds16(xb + gsw0 + 1024, ldst0 + 1024);
    }
    float pm = Mask[blockRow * 8 + tid];

    // ---- B fragments (loaded once per wave; lane-contiguous, L2-hot)
    bf16x8 Bf[8][2];
    #pragma unroll
    for (int h = 0; h < 8; ++h) {
        const unsigned short* pb = packedB + ((((h * 4 + w) * 2) * 64) + lane) * 8;
        Bf[h][0] = *(const bf16x8*)pb;
        Bf[h][1] = *(const bf16x8*)(pb + 512);
    }
    // ---- bias for this lane's output column (C-init values)
    float biasr[8];
    #pragma unroll
    for (int h = 0; h < 8; ++h) biasr[h] = bias[h * 64 + s];

    sM[0][smw] = pm;
    __syncthreads();        // vmcnt(0) drain: group-0 DMA + pm landed

    const int sz = (c & 7) << 3;        // read-side XOR (validated round 7)

    int cur = 0;
    #pragma unroll 1
    for (int grp = 0; grp < 4; ++grp) {
        const int gRow = blockRow + grp * GR;
        const bool more = (grp < 3);

        // issue next group's DMA into the free buffer RIGHT AWAY:
        // full group compute covers the latency; no reg round-trip.
        if (more) {
            const float* xb = X + (gRow + GR) * 64;
            float* ld = cur ? ldst0 : ldst1;
            gload_lds16(xb + gsw0, ld);
            gload_lds16(xb + gsw0 + 1024, ld + 1024);
            pm = Mask[(gRow + GR) * 8 + tid];
        }

        const float* sx = sX[cur];
        const float* sm = sM[cur];

        #pragma unroll
        for (int t = 0; t < 2; ++t) {
            const int rb = ((t << 4) + c) * 64;
            float4 x0 = *(const float4*)(&sx[rb + ((g << 3) ^ sz)]);
            float4 x1 = *(const float4*)(&sx[rb + (((g << 3) ^ sz) + 4)]);
            bf16x8 a0 = cvt8(x0, x1);   // logical cols [g*8, g*8+8)
            float4 x2 = *(const float4*)(&sx[rb + (((g << 3) + 32) ^ sz)]);
            float4 x3 = *(const float4*)(&sx[rb + ((((g << 3) + 32) ^ sz) + 4)]);
            bf16x8 a1 = cvt8(x2, x3);   // logical cols [32+g*8, ...)

            float o[4];
            // ---- half 1: h = 0..3 (acc live: 16 regs)
            {
                f32x4 acc[4];
                #pragma unroll
                for (int h = 0; h < 4; ++h) acc[h] = (f32x4)(biasr[h]);
                #pragma unroll
                for (int h = 0; h < 4; ++h) {
                    acc[h] = __builtin_amdgcn_mfma_f32_16x16x32_bf16(a0, Bf[h][0], acc[h], 0, 0, 0);
                    acc[h] = __builtin_amdgcn_mfma_f32_16x16x32_bf16(a1, Bf[h][1], acc[h], 0, 0, 0);
                }
                #pragma unroll
                for (int i = 0; i < 4; ++i) {
                    const int rr = (t << 4) + (g << 2) + i;
                    const float4 ml = *(const float4*)(&sm[rr * 12]);
                    float v = ml.x * acc[0][i];
                    v = fmaf(ml.y, acc[1][i], v);
                    v = fmaf(ml.z, acc[2][i], v);
                    v = fmaf(ml.w, acc[3][i], v);
                    o[i] = v;
                }
            }
            // ---- half 2: h = 4..7
            {
                f32x4 acc[4];
                #pragma unroll
                for (int h = 0; h < 4; ++h) acc[h] = (f32x4)(biasr[4 + h]);
                #pragma unroll
                for (int h = 0; h < 4; ++h) {
                    acc[h] = __builtin_amdgcn_mfma_f32_16x16x32_bf16(a0, Bf[4 + h][0], acc[h], 0, 0, 0);
                    acc[h] = __builtin_amdgcn_mfma_f32_16x16x32_bf16(a1, Bf[4 + h][1], acc[h], 0, 0, 0);
                }
                #pragma unroll
                for (int i = 0; i < 4; ++i) {
                    const int rr = (t << 4) + (g << 2) + i;
                    const float4 mh = *(const float4*)(&sm[rr * 12 + 4]);
                    float v = o[i];
                    v = fmaf(mh.x, acc[0][i], v);
                    v = fmaf(mh.y, acc[1][i], v);
                    v = fmaf(mh.z, acc[2][i], v);
                    v = fmaf(mh.w, acc[3][i], v);
                    Out[(gRow + rr) * 64 + s] = v;
                }
            }
        }

        if (more) sM[cur ^ 1][smw] = pm;   // pm's load had full compute to land
        __syncthreads();                   // also completes next group's DMA
        cur ^= 1;
    }
}

extern "C" void kernel_launch(void* const* d_in, const int* in_sizes, int n_in,
                              void* d_out, int out_size, void* d_ws, size_t ws_size,
                              hipStream_t stream) {
    const float* target = (const float*)d_in[0];   // (B,L,64)
    const float* hyper  = (const float*)d_in[1];   // (8,256)
    const float* mask   = (const float*)d_in[2];   // (B,L,8)
    const float* W1     = (const float*)d_in[3];   // (256,4096)
    const float* b1     = (const float*)d_in[4];   // (4096)
    const float* Wb     = (const float*)d_in[5];   // (256,64)
    const float* bb     = (const float*)d_in[6];   // (64)
    float* out = (float*)d_out;

    float* hw   = (float*)d_ws;                         // 32768 f32
    float* bias = hw + 8 * 4096;                        // 512 f32
    unsigned short* packed = (unsigned short*)(bias + 512); // 32768 bf16

    const int M = in_sizes[0] / 64;                     // 131072 rows

    hipLaunchKernelGGL(hypernet_kernel, dim3((8 * 4096 + 8 * 64) / 32), dim3(256),
                       0, stream, hyper, W1, b1, Wb, bb, hw, bias);
    hipLaunchKernelGGL(pack_kernel, dim3(512), dim3(64), 0, stream, hw, packed);
    hipLaunchKernelGGL(main_kernel, dim3(1024), dim3(256), 0, stream,
                       target, mask, packed, bias, out, M);
}

// Round 9
// 46.066 us; speedup vs baseline: 1.7939x; 1.7939x over previous
//
#include <hip/hip_runtime.h>
#include <hip/hip_bf16.h>

typedef __attribute__((ext_vector_type(8))) short bf16x8;
typedef __attribute__((ext_vector_type(4))) float f32x4;

static __device__ __forceinline__ unsigned short f2bf(float f) {
    unsigned int u = __float_as_uint(f);
    unsigned int rnd = 0x7FFFu + ((u >> 16) & 1u);
    return (unsigned short)((u + rnd) >> 16);
}

// pack two f32 -> 2xbf16 (RNE) using v_cvt_pk_bf16_f32
static __device__ __forceinline__ bf16x8 cvt8(float4 u, float4 v) {
    union { bf16x8 r; __hip_bfloat162 h[4]; } o;
    o.h[0] = __float22bfloat162_rn(float2{u.x, u.y});
    o.h[1] = __float22bfloat162_rn(float2{u.z, u.w});
    o.h[2] = __float22bfloat162_rn(float2{v.x, v.y});
    o.h[3] = __float22bfloat162_rn(float2{v.z, v.w});
    return o.r;
}

// ---------------- Kernel 1: hypernetwork hw = hyper@W1+b1, bias = hyper@Wb+bb
__global__ __launch_bounds__(256)
void hypernet_kernel(const float* __restrict__ hyper,   // (8,256)
                     const float* __restrict__ W1,      // (256,4096)
                     const float* __restrict__ b1,      // (4096)
                     const float* __restrict__ Wb,      // (256,64)
                     const float* __restrict__ bb,      // (64)
                     float* __restrict__ hw,            // ws: 8*4096
                     float* __restrict__ bias)          // ws: 8*64
{
    __shared__ float red[256];
    const int tid = threadIdx.x;
    const int p   = tid >> 5;          // 0..7  (d-range)
    const int jj  = tid & 31;          // 0..31 (output within block)
    const int o0  = blockIdx.x * 32;
    const int o   = o0 + jj;

    float acc = 0.f;
    if (o0 < 8 * 4096) {               // hw part (uniform per block)
        int h = o >> 12, j = o & 4095;
        const float* hr = hyper + (h << 8);
        #pragma unroll
        for (int i = 0; i < 32; ++i) {
            int d = (p << 5) + i;
            acc += hr[d] * W1[d * 4096 + j];
        }
    } else {                           // bias part
        int t = o - 8 * 4096;          // 0..511
        int h = t >> 6, s = t & 63;
        const float* hr = hyper + (h << 8);
        #pragma unroll
        for (int i = 0; i < 32; ++i) {
            int d = (p << 5) + i;
            acc += hr[d] * Wb[d * 64 + s];
        }
    }
    red[tid] = acc;
    __syncthreads();
    if (p == 0) {
        float sum = red[jj]       + red[32 + jj]  + red[64 + jj]  + red[96 + jj]
                  + red[128 + jj] + red[160 + jj] + red[192 + jj] + red[224 + jj];
        if (o0 < 8 * 4096) hw[o] = sum + b1[o & 4095];
        else {
            int t = o - 8 * 4096;
            bias[t] = sum + bb[t & 63];
        }
    }
}

// ---------------- Kernel 2: W[h] = down@up, packed directly into MFMA
// B-fragment order for v_mfma_f32_16x16x32_bf16 (validated in round 1).
__global__ void pack_kernel(const float* __restrict__ hw,          // 8*4096
                            unsigned short* __restrict__ packed)   // 32768 bf16
{
    int p = blockIdx.x * blockDim.x + threadIdx.x;  // 0..32767
    int b   = p & 7;
    int l   = (p >> 3) & 63;
    int kap = (p >> 9) & 1;
    int n   = p >> 10;                              // 0..31
    int k   = kap * 32 + ((l >> 4) << 3) + b;       // 0..63 (= target feature d)
    int col = (n << 4) + (l & 15);                  // 0..511
    int h = col >> 6, s = col & 63;
    const float* hwh = hw + h * 4096;
    float acc = 0.f;
    #pragma unroll
    for (int r = 0; r < 32; ++r)
        acc += hwh[k * 32 + r] * hwh[2048 + r * 64 + s];
    packed[p] = f2bf(acc);
}

// ---------------- Kernel 3: main — register-streaming GEMM, DISTANCE-2
// X prefetch (two tiles in flight, named reg sets pa/pb, static indexing).
// (256,3): the only non-spilling occupancy (rounds 3/5/6/8 all spilled at 4).
// 1024 blocks x 128 rows; masks staged once to stride-12 LDS (broadcast
// reads, <=2-way); bias as MFMA C-init; h-split acc; XCD-bijective swizzle.
#define TPW 8

__global__ __launch_bounds__(256, 3)
void main_kernel(const float* __restrict__ X,       // (M,64)
                 const float* __restrict__ Mask,    // (M,8)
                 const unsigned short* __restrict__ packedB,
                 const float* __restrict__ bias,    // (8,64)
                 float* __restrict__ Out,           // (M,64)
                 int M)
{
    __shared__ __align__(16) float sM[16 * TPW * 12];   // 128 rows x stride 12

    const int tid  = threadIdx.x;
    const int lane = tid & 63;
    const int w    = tid >> 6;          // wave id -> output col tile
    const int c    = lane & 15;         // A row-within-tile / D col-within-tile
    const int g    = lane >> 4;         // k-group / D row-group
    const int s    = (w << 4) + c;      // output column 0..63

    // XCD-bijective swizzle (gridDim multiple of 8): contiguous X per XCD
    const int cpx = gridDim.x >> 3;
    const int swz = (blockIdx.x & 7) * cpx + (blockIdx.x >> 3);
    const int rowBase = swz * (16 * TPW);

    // ---- stage all 128 rows' masks to LDS (1024 floats, stride-12)
    {
        float4 mv = *(const float4*)(Mask + rowBase * 8 + tid * 4);
        *(float4*)(&sM[(tid >> 1) * 12 + (tid & 1) * 4]) = mv;
    }

    // ---- B fragments (once per wave, L2-hot)
    bf16x8 Bf[8][2];
    #pragma unroll
    for (int h = 0; h < 8; ++h) {
        const unsigned short* pb = packedB + ((((h * 4 + w) * 2) * 64) + lane) * 8;
        Bf[h][0] = *(const bf16x8*)pb;
        Bf[h][1] = *(const bf16x8*)(pb + 512);
    }
    // ---- bias for this lane's output column (MFMA C-init)
    float biasr[8];
    #pragma unroll
    for (int h = 0; h < 8; ++h) biasr[h] = bias[h * 64 + s];

    // lane's X base: row (rowBase + c), word cols [g*8 .. ) / [32+g*8 .. )
    const float* xrow = X + (rowBase + c) * 64 + (g << 3);

    // ---- distance-2 prefetch: tiles 0 and 1 in flight
    float4 pa0 = *(const float4*)(xrow);
    float4 pa1 = *(const float4*)(xrow + 4);
    float4 pa2 = *(const float4*)(xrow + 32);
    float4 pa3 = *(const float4*)(xrow + 36);
    float4 pb0 = *(const float4*)(xrow + 1024);
    float4 pb1 = *(const float4*)(xrow + 1028);
    float4 pb2 = *(const float4*)(xrow + 1056);
    float4 pb3 = *(const float4*)(xrow + 1060);

    __syncthreads();

    auto compute = [&](int t, bf16x8 a0, bf16x8 a1) {
        float o[4];
        {   // h = 0..3
            f32x4 acc[4];
            #pragma unroll
            for (int h = 0; h < 4; ++h) acc[h] = (f32x4)(biasr[h]);
            #pragma unroll
            for (int h = 0; h < 4; ++h) {
                acc[h] = __builtin_amdgcn_mfma_f32_16x16x32_bf16(a0, Bf[h][0], acc[h], 0, 0, 0);
                acc[h] = __builtin_amdgcn_mfma_f32_16x16x32_bf16(a1, Bf[h][1], acc[h], 0, 0, 0);
            }
            #pragma unroll
            for (int i = 0; i < 4; ++i) {
                const int rr = t * 16 + (g << 2) + i;
                const float4 ml = *(const float4*)(&sM[rr * 12]);
                float v = ml.x * acc[0][i];
                v = fmaf(ml.y, acc[1][i], v);
                v = fmaf(ml.z, acc[2][i], v);
                v = fmaf(ml.w, acc[3][i], v);
                o[i] = v;
            }
        }
        {   // h = 4..7
            f32x4 acc[4];
            #pragma unroll
            for (int h = 0; h < 4; ++h) acc[h] = (f32x4)(biasr[4 + h]);
            #pragma unroll
            for (int h = 0; h < 4; ++h) {
                acc[h] = __builtin_amdgcn_mfma_f32_16x16x32_bf16(a0, Bf[4 + h][0], acc[h], 0, 0, 0);
                acc[h] = __builtin_amdgcn_mfma_f32_16x16x32_bf16(a1, Bf[4 + h][1], acc[h], 0, 0, 0);
            }
            #pragma unroll
            for (int i = 0; i < 4; ++i) {
                const int rr = t * 16 + (g << 2) + i;
                const float4 mh = *(const float4*)(&sM[rr * 12 + 4]);
                float v = o[i];
                v = fmaf(mh.x, acc[0][i], v);
                v = fmaf(mh.y, acc[1][i], v);
                v = fmaf(mh.z, acc[2][i], v);
                v = fmaf(mh.w, acc[3][i], v);
                Out[(rowBase + rr) * 64 + s] = v;
            }
        }
    };

    #pragma unroll 1
    for (int tt = 0; tt < TPW; tt += 2) {
        // ---- phase A: tile tt from pa; refill pa with tile tt+2
        {
            bf16x8 a0 = cvt8(pa0, pa1);
            bf16x8 a1 = cvt8(pa2, pa3);
            if (tt + 2 < TPW) {
                const float* xp = xrow + (tt + 2) * 1024;
                pa0 = *(const float4*)(xp);
                pa1 = *(const float4*)(xp + 4);
                pa2 = *(const float4*)(xp + 32);
                pa3 = *(const float4*)(xp + 36);
            }
            compute(tt, a0, a1);
        }
        // ---- phase B: tile tt+1 from pb; refill pb with tile tt+3
        {
            bf16x8 a0 = cvt8(pb0, pb1);
            bf16x8 a1 = cvt8(pb2, pb3);
            if (tt + 3 < TPW) {
                const float* xp = xrow + (tt + 3) * 1024;
                pb0 = *(const float4*)(xp);
                pb1 = *(const float4*)(xp + 4);
                pb2 = *(const float4*)(xp + 32);
                pb3 = *(const float4*)(xp + 36);
            }
            compute(tt + 1, a0, a1);
        }
    }
}

extern "C" void kernel_launch(void* const* d_in, const int* in_sizes, int n_in,
                              void* d_out, int out_size, void* d_ws, size_t ws_size,
                              hipStream_t stream) {
    const float* target = (const float*)d_in[0];   // (B,L,64)
    const float* hyper  = (const float*)d_in[1];   // (8,256)
    const float* mask   = (const float*)d_in[2];   // (B,L,8)
    const float* W1     = (const float*)d_in[3];   // (256,4096)
    const float* b1     = (const float*)d_in[4];   // (4096)
    const float* Wb     = (const float*)d_in[5];   // (256,64)
    const float* bb     = (const float*)d_in[6];   // (64)
    float* out = (float*)d_out;

    float* hw   = (float*)d_ws;                         // 32768 f32
    float* bias = hw + 8 * 4096;                        // 512 f32
    unsigned short* packed = (unsigned short*)(bias + 512); // 32768 bf16

    const int M = in_sizes[0] / 64;                     // 131072 rows

    hipLaunchKernelGGL(hypernet_kernel, dim3((8 * 4096 + 8 * 64) / 32), dim3(256),
                       0, stream, hyper, W1, b1, Wb, bb, hw, bias);
    hipLaunchKernelGGL(pack_kernel, dim3(512), dim3(64), 0, stream, hw, packed);
    hipLaunchKernelGGL(main_kernel, dim3(M / (16 * TPW)), dim3(256), 0, stream,
                       target, mask, packed, bias, out, M);
}

// Round 10
// 42.260 us; speedup vs baseline: 1.9555x; 1.0901x over previous
//
#include <hip/hip_runtime.h>
#include <hip/hip_bf16.h>

typedef __attribute__((ext_vector_type(8))) short bf16x8;
typedef __attribute__((ext_vector_type(4))) float f32x4;

static __device__ __forceinline__ unsigned short f2bf(float f) {
    unsigned int u = __float_as_uint(f);
    unsigned int rnd = 0x7FFFu + ((u >> 16) & 1u);
    return (unsigned short)((u + rnd) >> 16);
}

// pack two f32 -> 2xbf16 (RNE) using v_cvt_pk_bf16_f32
static __device__ __forceinline__ bf16x8 cvt8(float4 u, float4 v) {
    union { bf16x8 r; __hip_bfloat162 h[4]; } o;
    o.h[0] = __float22bfloat162_rn(float2{u.x, u.y});
    o.h[1] = __float22bfloat162_rn(float2{u.z, u.w});
    o.h[2] = __float22bfloat162_rn(float2{v.x, v.y});
    o.h[3] = __float22bfloat162_rn(float2{v.z, v.w});
    return o.r;
}

// ---------------- Kernel 1: hypernetwork hw = hyper@W1+b1, bias = hyper@Wb+bb
__global__ __launch_bounds__(256)
void hypernet_kernel(const float* __restrict__ hyper,   // (8,256)
                     const float* __restrict__ W1,      // (256,4096)
                     const float* __restrict__ b1,      // (4096)
                     const float* __restrict__ Wb,      // (256,64)
                     const float* __restrict__ bb,      // (64)
                     float* __restrict__ hw,            // ws: 8*4096
                     float* __restrict__ bias)          // ws: 8*64
{
    __shared__ float red[256];
    const int tid = threadIdx.x;
    const int p   = tid >> 5;          // 0..7  (d-range)
    const int jj  = tid & 31;          // 0..31 (output within block)
    const int o0  = blockIdx.x * 32;
    const int o   = o0 + jj;

    float acc = 0.f;
    if (o0 < 8 * 4096) {               // hw part (uniform per block)
        int h = o >> 12, j = o & 4095;
        const float* hr = hyper + (h << 8);
        #pragma unroll
        for (int i = 0; i < 32; ++i) {
            int d = (p << 5) + i;
            acc += hr[d] * W1[d * 4096 + j];
        }
    } else {                           // bias part
        int t = o - 8 * 4096;          // 0..511
        int h = t >> 6, s = t & 63;
        const float* hr = hyper + (h << 8);
        #pragma unroll
        for (int i = 0; i < 32; ++i) {
            int d = (p << 5) + i;
            acc += hr[d] * Wb[d * 64 + s];
        }
    }
    red[tid] = acc;
    __syncthreads();
    if (p == 0) {
        float sum = red[jj]       + red[32 + jj]  + red[64 + jj]  + red[96 + jj]
                  + red[128 + jj] + red[160 + jj] + red[192 + jj] + red[224 + jj];
        if (o0 < 8 * 4096) hw[o] = sum + b1[o & 4095];
        else {
            int t = o - 8 * 4096;
            bias[t] = sum + bb[t & 63];
        }
    }
}

// ---------------- Kernel 2: W[h] = down@up, packed directly into MFMA
// B-fragment order for v_mfma_f32_16x16x32_bf16 (validated in round 1).
__global__ void pack_kernel(const float* __restrict__ hw,          // 8*4096
                            unsigned short* __restrict__ packed)   // 32768 bf16
{
    int p = blockIdx.x * blockDim.x + threadIdx.x;  // 0..32767
    int b   = p & 7;
    int l   = (p >> 3) & 63;
    int kap = (p >> 9) & 1;
    int n   = p >> 10;                              // 0..31
    int k   = kap * 32 + ((l >> 4) << 3) + b;       // 0..63 (= target feature d)
    int col = (n << 4) + (l & 15);                  // 0..511
    int h = col >> 6, s = col & 63;
    const float* hwh = hw + h * 4096;
    float acc = 0.f;
    #pragma unroll
    for (int r = 0; r < 32; ++r)
        acc += hwh[k * 32 + r] * hwh[2048 + r * 64 + s];
    packed[p] = f2bf(acc);
}

// ---------------- Kernel 3: main — round-4 structure at TPW=2.
// 4096 blocks x 32 rows: block-phase diversity is the ONLY lever that has
// moved this kernel (2048x64 -> 30us vs 1024x128 -> 47us; same code).
// (256,3) = only non-spilling occupancy. Masks in LDS (broadcast reads),
// dist-1 X prefetch, bias folded as MFMA C-init (validated, -32 VALU/tile).
#define TPW 2   // row-tiles per wave; block covers 32 rows

__global__ __launch_bounds__(256, 3)
void main_kernel(const float* __restrict__ X,       // (M,64)
                 const float* __restrict__ Mask,    // (M,8)
                 const unsigned short* __restrict__ packedB,
                 const float* __restrict__ bias,    // (8,64)
                 float* __restrict__ Out)           // (M,64)
{
    __shared__ float sM[16 * TPW * 8];  // 32 rows x 8 masks = 1 KB

    const int tid  = threadIdx.x;
    const int lane = tid & 63;
    const int w    = tid >> 6;          // wave id 0..3 -> output col tile
    const int c    = lane & 15;         // A row-within-tile / D col-within-tile
    const int g    = lane >> 4;         // k-group / D row-group
    const int rowBase = blockIdx.x * (16 * TPW);
    const int s = (w << 4) + c;         // output column 0..63

    // ---- stage mask tile to LDS: 256 floats, 1 per thread (coalesced)
    sM[tid] = Mask[(long)rowBase * 8 + tid];

    // ---- B fragments for this wave (L2-hot 64KB buffer)
    bf16x8 Bf[8][2];
    #pragma unroll
    for (int h = 0; h < 8; ++h) {
        const unsigned short* pb = packedB + ((((h * 4 + w) * 2) * 64) + lane) * 8;
        Bf[h][0] = *(const bf16x8*)pb;
        Bf[h][1] = *(const bf16x8*)(pb + 512);
    }

    // ---- bias for this lane's output column (MFMA C-init values)
    float biasr[8];
    #pragma unroll
    for (int h = 0; h < 8; ++h) biasr[h] = bias[h * 64 + s];

    // lane reads X row (rowBase + t*16 + c), cols [g*8,g*8+8) and [32+g*8, ...)
    const float* xrow = X + (long)(rowBase + c) * 64 + (g << 3);

    // ---- prologue: prefetch tile 0
    float4 px0 = *(const float4*)(xrow);
    float4 px1 = *(const float4*)(xrow + 4);
    float4 px2 = *(const float4*)(xrow + 32);
    float4 px3 = *(const float4*)(xrow + 36);

    __syncthreads();

    #pragma unroll
    for (int t = 0; t < TPW; ++t) {
        float4 cx0 = px0, cx1 = px1, cx2 = px2, cx3 = px3;

        // prefetch X for tile t+1
        if (t + 1 < TPW) {
            const float* xp = xrow + (t + 1) * 1024;
            px0 = *(const float4*)(xp);
            px1 = *(const float4*)(xp + 4);
            px2 = *(const float4*)(xp + 32);
            px3 = *(const float4*)(xp + 36);
        }

        bf16x8 a0 = cvt8(cx0, cx1);     // cols [g*8, g*8+8)
        bf16x8 a1 = cvt8(cx2, cx3);     // cols [32+g*8, 32+g*8+8)

        f32x4 acc[8];
        #pragma unroll
        for (int h = 0; h < 8; ++h) acc[h] = (f32x4)(biasr[h]);   // bias C-init
        #pragma unroll
        for (int h = 0; h < 8; ++h) {
            acc[h] = __builtin_amdgcn_mfma_f32_16x16x32_bf16(a0, Bf[h][0], acc[h], 0, 0, 0);
            acc[h] = __builtin_amdgcn_mfma_f32_16x16x32_bf16(a1, Bf[h][1], acc[h], 0, 0, 0);
        }

        // epilogue: out[row,s] = sum_h m[row,h] * (Z + bias)
        // masks via LDS broadcast (16 lanes share each address)
        #pragma unroll
        for (int i = 0; i < 4; ++i) {
            const int r = t * 16 + (g << 2) + i;
            const float4 ml = *(const float4*)(&sM[r * 8]);
            const float4 mh = *(const float4*)(&sM[r * 8 + 4]);
            float o = ml.x * acc[0][i];
            o = fmaf(ml.y, acc[1][i], o);
            o = fmaf(ml.z, acc[2][i], o);
            o = fmaf(ml.w, acc[3][i], o);
            o = fmaf(mh.x, acc[4][i], o);
            o = fmaf(mh.y, acc[5][i], o);
            o = fmaf(mh.z, acc[6][i], o);
            o = fmaf(mh.w, acc[7][i], o);
            Out[(long)(rowBase + r) * 64 + s] = o;
        }
    }
}

extern "C" void kernel_launch(void* const* d_in, const int* in_sizes, int n_in,
                              void* d_out, int out_size, void* d_ws, size_t ws_size,
                              hipStream_t stream) {
    const float* target = (const float*)d_in[0];   // (B,L,64)
    const float* hyper  = (const float*)d_in[1];   // (8,256)
    const float* mask   = (const float*)d_in[2];   // (B,L,8)
    const float* W1     = (const float*)d_in[3];   // (256,4096)
    const float* b1     = (const float*)d_in[4];   // (4096)
    const float* Wb     = (const float*)d_in[5];   // (256,64)
    const float* bb     = (const float*)d_in[6];   // (64)
    float* out = (float*)d_out;

    float* hw   = (float*)d_ws;                         // 32768 f32
    float* bias = hw + 8 * 4096;                        // 512 f32
    unsigned short* packed = (unsigned short*)(bias + 512); // 32768 bf16

    const int M = in_sizes[0] / 64;                     // 131072 rows

    hipLaunchKernelGGL(hypernet_kernel, dim3((8 * 4096 + 8 * 64) / 32), dim3(256),
                       0, stream, hyper, W1, b1, Wb, bb, hw, bias);
    hipLaunchKernelGGL(pack_kernel, dim3(512), dim3(64), 0, stream, hw, packed);
    hipLaunchKernelGGL(main_kernel, dim3(M / (16 * TPW)), dim3(256), 0, stream,
                       target, mask, packed, bias, out);
}

// Round 11
// 39.918 us; speedup vs baseline: 2.0702x; 1.0587x over previous
//
#include <hip/hip_runtime.h>
#include <hip/hip_bf16.h>

typedef __attribute__((ext_vector_type(8))) short bf16x8;
typedef __attribute__((ext_vector_type(4))) float f32x4;

static __device__ __forceinline__ unsigned short f2bf(float f) {
    unsigned int u = __float_as_uint(f);
    unsigned int rnd = 0x7FFFu + ((u >> 16) & 1u);
    return (unsigned short)((u + rnd) >> 16);
}

// pack two f32 -> 2xbf16 (RNE) using v_cvt_pk_bf16_f32
static __device__ __forceinline__ bf16x8 cvt8(float4 u, float4 v) {
    union { bf16x8 r; __hip_bfloat162 h[4]; } o;
    o.h[0] = __float22bfloat162_rn(float2{u.x, u.y});
    o.h[1] = __float22bfloat162_rn(float2{u.z, u.w});
    o.h[2] = __float22bfloat162_rn(float2{v.x, v.y});
    o.h[3] = __float22bfloat162_rn(float2{v.z, v.w});
    return o.r;
}

// ---------------- Kernel 1: hypernetwork hw = hyper@W1+b1, bias = hyper@Wb+bb
__global__ __launch_bounds__(256)
void hypernet_kernel(const float* __restrict__ hyper,   // (8,256)
                     const float* __restrict__ W1,      // (256,4096)
                     const float* __restrict__ b1,      // (4096)
                     const float* __restrict__ Wb,      // (256,64)
                     const float* __restrict__ bb,      // (64)
                     float* __restrict__ hw,            // ws: 8*4096
                     float* __restrict__ bias)          // ws: 8*64
{
    __shared__ float red[256];
    const int tid = threadIdx.x;
    const int p   = tid >> 5;          // 0..7  (d-range)
    const int jj  = tid & 31;          // 0..31 (output within block)
    const int o0  = blockIdx.x * 32;
    const int o   = o0 + jj;

    float acc = 0.f;
    if (o0 < 8 * 4096) {               // hw part (uniform per block)
        int h = o >> 12, j = o & 4095;
        const float* hr = hyper + (h << 8);
        #pragma unroll
        for (int i = 0; i < 32; ++i) {
            int d = (p << 5) + i;
            acc += hr[d] * W1[d * 4096 + j];
        }
    } else {                           // bias part
        int t = o - 8 * 4096;          // 0..511
        int h = t >> 6, s = t & 63;
        const float* hr = hyper + (h << 8);
        #pragma unroll
        for (int i = 0; i < 32; ++i) {
            int d = (p << 5) + i;
            acc += hr[d] * Wb[d * 64 + s];
        }
    }
    red[tid] = acc;
    __syncthreads();
    if (p == 0) {
        float sum = red[jj]       + red[32 + jj]  + red[64 + jj]  + red[96 + jj]
                  + red[128 + jj] + red[160 + jj] + red[192 + jj] + red[224 + jj];
        if (o0 < 8 * 4096) hw[o] = sum + b1[o & 4095];
        else {
            int t = o - 8 * 4096;
            bias[t] = sum + bb[t & 63];
        }
    }
}

// ---------------- Kernel 2: W[h] = down@up, packed directly into MFMA
// B-fragment order for v_mfma_f32_16x16x32_bf16 (validated in round 1).
__global__ void pack_kernel(const float* __restrict__ hw,          // 8*4096
                            unsigned short* __restrict__ packed)   // 32768 bf16
{
    int p = blockIdx.x * blockDim.x + threadIdx.x;  // 0..32767
    int b   = p & 7;
    int l   = (p >> 3) & 63;
    int kap = (p >> 9) & 1;
    int n   = p >> 10;                              // 0..31
    int k   = kap * 32 + ((l >> 4) << 3) + b;       // 0..63 (= target feature d)
    int col = (n << 4) + (l & 15);                  // 0..511
    int h = col >> 6, s = col & 63;
    const float* hwh = hw + h * 4096;
    float acc = 0.f;
    #pragma unroll
    for (int r = 0; r < 32; ++r)
        acc += hwh[k * 32 + r] * hwh[2048 + r * 64 + s];
    packed[p] = f2bf(acc);
}

// ---------------- Kernel 3: main — round-4 structure (the empirical optimum:
// 2048 blocks x 64 rows, TPW=4) + bias folded as MFMA C-init.
// Block-granularity curve mapped over rounds 2/4/10: 128r->47us, 64r->30us,
// 32r->40us. (256,3) = only non-spilling occupancy (rounds 3/5/6/8 spilled
// at 4 waves/EU). Masks in LDS broadcast; dist-1 X prefetch.
#define TPW 4   // row-tiles per wave; block covers 64 rows

__global__ __launch_bounds__(256, 3)
void main_kernel(const float* __restrict__ X,       // (M,64)
                 const float* __restrict__ Mask,    // (M,8)
                 const unsigned short* __restrict__ packedB,
                 const float* __restrict__ bias,    // (8,64)
                 float* __restrict__ Out)           // (M,64)
{
    __shared__ float sM[16 * TPW * 8];  // 2 KB: 64 rows x 8 masks

    const int tid  = threadIdx.x;
    const int lane = tid & 63;
    const int w    = tid >> 6;          // wave id 0..3 -> output col tile
    const int c    = lane & 15;         // A row-within-tile / D col-within-tile
    const int g    = lane >> 4;         // k-group / D row-group
    const int rowBase = blockIdx.x * (16 * TPW);
    const int s = (w << 4) + c;         // output column 0..63

    // ---- stage mask tile to LDS: 512 floats = 256 float2 (coalesced)
    {
        const float2* Mv = (const float2*)(Mask + (long)rowBase * 8);
        ((float2*)sM)[tid] = Mv[tid];
    }

    // ---- B fragments for this wave (L2-hot 64KB buffer)
    bf16x8 Bf[8][2];
    #pragma unroll
    for (int h = 0; h < 8; ++h) {
        const unsigned short* pb = packedB + ((((h * 4 + w) * 2) * 64) + lane) * 8;
        Bf[h][0] = *(const bf16x8*)pb;
        Bf[h][1] = *(const bf16x8*)(pb + 512);
    }

    // ---- bias for this lane's output column (MFMA C-init values)
    float biasr[8];
    #pragma unroll
    for (int h = 0; h < 8; ++h) biasr[h] = bias[h * 64 + s];

    // lane reads X row (rowBase + t*16 + c), cols [g*8,g*8+8) and [32+g*8, ...)
    const float* xrow = X + (long)(rowBase + c) * 64 + (g << 3);

    // ---- prologue: prefetch tile 0
    float4 px0 = *(const float4*)(xrow);
    float4 px1 = *(const float4*)(xrow + 4);
    float4 px2 = *(const float4*)(xrow + 32);
    float4 px3 = *(const float4*)(xrow + 36);

    __syncthreads();

    #pragma unroll 2
    for (int t = 0; t < TPW; ++t) {
        float4 cx0 = px0, cx1 = px1, cx2 = px2, cx3 = px3;

        // prefetch X for tile t+1
        if (t + 1 < TPW) {
            const float* xp = xrow + (t + 1) * 1024;
            px0 = *(const float4*)(xp);
            px1 = *(const float4*)(xp + 4);
            px2 = *(const float4*)(xp + 32);
            px3 = *(const float4*)(xp + 36);
        }

        bf16x8 a0 = cvt8(cx0, cx1);     // cols [g*8, g*8+8)
        bf16x8 a1 = cvt8(cx2, cx3);     // cols [32+g*8, 32+g*8+8)

        f32x4 acc[8];
        #pragma unroll
        for (int h = 0; h < 8; ++h) acc[h] = (f32x4)(biasr[h]);   // bias C-init
        #pragma unroll
        for (int h = 0; h < 8; ++h) {
            acc[h] = __builtin_amdgcn_mfma_f32_16x16x32_bf16(a0, Bf[h][0], acc[h], 0, 0, 0);
            acc[h] = __builtin_amdgcn_mfma_f32_16x16x32_bf16(a1, Bf[h][1], acc[h], 0, 0, 0);
        }

        // epilogue: out[row,s] = sum_h m[row,h] * (Z + bias); acc = Z + bias
        // masks via LDS broadcast (16 lanes share each address)
        #pragma unroll
        for (int i = 0; i < 4; ++i) {
            const int r = t * 16 + (g << 2) + i;
            const float4 ml = *(const float4*)(&sM[r * 8]);
            const float4 mh = *(const float4*)(&sM[r * 8 + 4]);
            float o = ml.x * acc[0][i];
            o = fmaf(ml.y, acc[1][i], o);
            o = fmaf(ml.z, acc[2][i], o);
            o = fmaf(ml.w, acc[3][i], o);
            o = fmaf(mh.x, acc[4][i], o);
            o = fmaf(mh.y, acc[5][i], o);
            o = fmaf(mh.z, acc[6][i], o);
            o = fmaf(mh.w, acc[7][i], o);
            Out[(long)(rowBase + r) * 64 + s] = o;
        }
    }
}

extern "C" void kernel_launch(void* const* d_in, const int* in_sizes, int n_in,
                              void* d_out, int out_size, void* d_ws, size_t ws_size,
                              hipStream_t stream) {
    const float* target = (const float*)d_in[0];   // (B,L,64)
    const float* hyper  = (const float*)d_in[1];   // (8,256)
    const float* mask   = (const float*)d_in[2];   // (B,L,8)
    const float* W1     = (const float*)d_in[3];   // (256,4096)
    const float* b1     = (const float*)d_in[4];   // (4096)
    const float* Wb     = (const float*)d_in[5];   // (256,64)
    const float* bb     = (const float*)d_in[6];   // (64)
    float* out = (float*)d_out;

    float* hw   = (float*)d_ws;                         // 32768 f32
    float* bias = hw + 8 * 4096;                        // 512 f32
    unsigned short* packed = (unsigned short*)(bias + 512); // 32768 bf16

    const int M = in_sizes[0] / 64;                     // 131072 rows

    hipLaunchKernelGGL(hypernet_kernel, dim3((8 * 4096 + 8 * 64) / 32), dim3(256),
                       0, stream, hyper, W1, b1, Wb, bb, hw, bias);
    hipLaunchKernelGGL(pack_kernel, dim3(512), dim3(64), 0, stream, hw, packed);
    hipLaunchKernelGGL(main_kernel, dim3(M / (16 * TPW)), dim3(256), 0, stream,
                       target, mask, packed, bias, out);
}

// Round 12
// 36.522 us; speedup vs baseline: 2.2627x; 1.0930x over previous
//
#include <hip/hip_runtime.h>
#include <hip/hip_bf16.h>

typedef __attribute__((ext_vector_type(8))) short bf16x8;
typedef __attribute__((ext_vector_type(4))) float f32x4;

static __device__ __forceinline__ unsigned short f2bf(float f) {
    unsigned int u = __float_as_uint(f);
    unsigned int rnd = 0x7FFFu + ((u >> 16) & 1u);
    return (unsigned short)((u + rnd) >> 16);
}

// pack two f32 -> 2xbf16 (RNE) using v_cvt_pk_bf16_f32
static __device__ __forceinline__ bf16x8 cvt8(float4 u, float4 v) {
    union { bf16x8 r; __hip_bfloat162 h[4]; } o;
    o.h[0] = __float22bfloat162_rn(float2{u.x, u.y});
    o.h[1] = __float22bfloat162_rn(float2{u.z, u.w});
    o.h[2] = __float22bfloat162_rn(float2{v.x, v.y});
    o.h[3] = __float22bfloat162_rn(float2{v.z, v.w});
    return o.r;
}

// ---------------- Kernel 1: hypernetwork hw = hyper@W1+b1, bias = hyper@Wb+bb
__global__ __launch_bounds__(256)
void hypernet_kernel(const float* __restrict__ hyper,   // (8,256)
                     const float* __restrict__ W1,      // (256,4096)
                     const float* __restrict__ b1,      // (4096)
                     const float* __restrict__ Wb,      // (256,64)
                     const float* __restrict__ bb,      // (64)
                     float* __restrict__ hw,            // ws: 8*4096
                     float* __restrict__ bias)          // ws: 8*64
{
    __shared__ float red[256];
    const int tid = threadIdx.x;
    const int p   = tid >> 5;          // 0..7  (d-range)
    const int jj  = tid & 31;          // 0..31 (output within block)
    const int o0  = blockIdx.x * 32;
    const int o   = o0 + jj;

    float acc = 0.f;
    if (o0 < 8 * 4096) {               // hw part (uniform per block)
        int h = o >> 12, j = o & 4095;
        const float* hr = hyper + (h << 8);
        #pragma unroll
        for (int i = 0; i < 32; ++i) {
            int d = (p << 5) + i;
            acc += hr[d] * W1[d * 4096 + j];
        }
    } else {                           // bias part
        int t = o - 8 * 4096;          // 0..511
        int h = t >> 6, s = t & 63;
        const float* hr = hyper + (h << 8);
        #pragma unroll
        for (int i = 0; i < 32; ++i) {
            int d = (p << 5) + i;
            acc += hr[d] * Wb[d * 64 + s];
        }
    }
    red[tid] = acc;
    __syncthreads();
    if (p == 0) {
        float sum = red[jj]       + red[32 + jj]  + red[64 + jj]  + red[96 + jj]
                  + red[128 + jj] + red[160 + jj] + red[192 + jj] + red[224 + jj];
        if (o0 < 8 * 4096) hw[o] = sum + b1[o & 4095];
        else {
            int t = o - 8 * 4096;
            bias[t] = sum + bb[t & 63];
        }
    }
}

// ---------------- Kernel 2: W[h] = down@up, packed directly into MFMA
// B-fragment order for v_mfma_f32_16x16x32_bf16 (validated in round 1).
// 64-thread blocks -> 512 blocks (2/CU) instead of 128 (0.5/CU).
__global__ void pack_kernel(const float* __restrict__ hw,          // 8*4096
                            unsigned short* __restrict__ packed)   // 32768 bf16
{
    int p = blockIdx.x * blockDim.x + threadIdx.x;  // 0..32767
    int b   = p & 7;
    int l   = (p >> 3) & 63;
    int kap = (p >> 9) & 1;
    int n   = p >> 10;                              // 0..31
    int k   = kap * 32 + ((l >> 4) << 3) + b;       // 0..63 (= target feature d)
    int col = (n << 4) + (l & 15);                  // 0..511
    int h = col >> 6, s = col & 63;
    const float* hwh = hw + h * 4096;
    float acc = 0.f;
    #pragma unroll
    for (int r = 0; r < 32; ++r)
        acc += hwh[k * 32 + r] * hwh[2048 + r * 64 + s];
    packed[p] = f2bf(acc);
}

// ---------------- Kernel 3: main — EXACT round-4 structure (best measured:
// 36.8 us total). 2048 blocks x 64 rows, TPW=4, (256,3), masks in LDS
// broadcast, dist-1 X prefetch, bias added in EPILOGUE (C-init variant
// measured -8%, round 11). Do not refold without A/B.
#define TPW 4   // row-tiles per wave; block covers 64 rows

__global__ __launch_bounds__(256, 3)
void main_kernel(const float* __restrict__ X,       // (M,64)
                 const float* __restrict__ Mask,    // (M,8)
                 const unsigned short* __restrict__ packedB,
                 const float* __restrict__ bias,    // (8,64)
                 float* __restrict__ Out)           // (M,64)
{
    __shared__ float sM[16 * TPW * 8];  // 2 KB: 64 rows x 8 masks

    const int tid  = threadIdx.x;
    const int lane = tid & 63;
    const int w    = tid >> 6;          // wave id 0..3 -> output col tile
    const int c    = lane & 15;         // A row-within-tile / D col-within-tile
    const int g    = lane >> 4;         // k-group / D row-group
    const int rowBase = blockIdx.x * (16 * TPW);
    const int s = (w << 4) + c;         // output column 0..63

    // ---- stage mask tile to LDS: 512 floats = 256 float2 (coalesced)
    {
        const float2* Mv = (const float2*)(Mask + (long)rowBase * 8);
        ((float2*)sM)[tid] = Mv[tid];
    }

    // ---- B fragments for this wave (L2-hot 64KB buffer)
    bf16x8 Bf[8][2];
    #pragma unroll
    for (int h = 0; h < 8; ++h) {
        const unsigned short* pb = packedB + ((((h * 4 + w) * 2) * 64) + lane) * 8;
        Bf[h][0] = *(const bf16x8*)pb;
        Bf[h][1] = *(const bf16x8*)(pb + 512);
    }

    // ---- bias for this lane's output column
    float biasr[8];
    #pragma unroll
    for (int h = 0; h < 8; ++h) biasr[h] = bias[h * 64 + s];

    // lane reads X row (rowBase + t*16 + c), cols [g*8,g*8+8) and [32+g*8, ...)
    const float* xrow = X + (long)(rowBase + c) * 64 + (g << 3);

    // ---- prologue: prefetch tile 0
    float4 px0 = *(const float4*)(xrow);
    float4 px1 = *(const float4*)(xrow + 4);
    float4 px2 = *(const float4*)(xrow + 32);
    float4 px3 = *(const float4*)(xrow + 36);

    __syncthreads();

    #pragma unroll 2
    for (int t = 0; t < TPW; ++t) {
        float4 cx0 = px0, cx1 = px1, cx2 = px2, cx3 = px3;

        // prefetch X for tile t+1
        if (t + 1 < TPW) {
            const float* xp = xrow + (t + 1) * 1024;
            px0 = *(const float4*)(xp);
            px1 = *(const float4*)(xp + 4);
            px2 = *(const float4*)(xp + 32);
            px3 = *(const float4*)(xp + 36);
        }

        bf16x8 a0 = cvt8(cx0, cx1);     // cols [g*8, g*8+8)
        bf16x8 a1 = cvt8(cx2, cx3);     // cols [32+g*8, 32+g*8+8)

        f32x4 acc[8];
        #pragma unroll
        for (int h = 0; h < 8; ++h) acc[h] = (f32x4)(0.f);
        #pragma unroll
        for (int h = 0; h < 8; ++h) {
            acc[h] = __builtin_amdgcn_mfma_f32_16x16x32_bf16(a0, Bf[h][0], acc[h], 0, 0, 0);
            acc[h] = __builtin_amdgcn_mfma_f32_16x16x32_bf16(a1, Bf[h][1], acc[h], 0, 0, 0);
        }

        // epilogue: out[row,s] = sum_h m[row,h] * (Z + bias)
        // masks via LDS broadcast (16 lanes share each address)
        #pragma unroll
        for (int i = 0; i < 4; ++i) {
            const int r = t * 16 + (g << 2) + i;
            const float4 ml = *(const float4*)(&sM[r * 8]);
            const float4 mh = *(const float4*)(&sM[r * 8 + 4]);
            float o = ml.x * (acc[0][i] + biasr[0]);
            o = fmaf(ml.y, acc[1][i] + biasr[1], o);
            o = fmaf(ml.z, acc[2][i] + biasr[2], o);
            o = fmaf(ml.w, acc[3][i] + biasr[3], o);
            o = fmaf(mh.x, acc[4][i] + biasr[4], o);
            o = fmaf(mh.y, acc[5][i] + biasr[5], o);
            o = fmaf(mh.z, acc[6][i] + biasr[6], o);
            o = fmaf(mh.w, acc[7][i] + biasr[7], o);
            Out[(long)(rowBase + r) * 64 + s] = o;
        }
    }
}

extern "C" void kernel_launch(void* const* d_in, const int* in_sizes, int n_in,
                              void* d_out, int out_size, void* d_ws, size_t ws_size,
                              hipStream_t stream) {
    const float* target = (const float*)d_in[0];   // (B,L,64)
    const float* hyper  = (const float*)d_in[1];   // (8,256)
    const float* mask   = (const float*)d_in[2];   // (B,L,8)
    const float* W1     = (const float*)d_in[3];   // (256,4096)
    const float* b1     = (const float*)d_in[4];   // (4096)
    const float* Wb     = (const float*)d_in[5];   // (256,64)
    const float* bb     = (const float*)d_in[6];   // (64)
    float* out = (float*)d_out;

    float* hw   = (float*)d_ws;                         // 32768 f32
    float* bias = hw + 8 * 4096;                        // 512 f32
    unsigned short* packed = (unsigned short*)(bias + 512); // 32768 bf16

    const int M = in_sizes[0] / 64;                     // 131072 rows

    hipLaunchKernelGGL(hypernet_kernel, dim3((8 * 4096 + 8 * 64) / 32), dim3(256),
                       0, stream, hyper, W1, b1, Wb, bb, hw, bias);
    hipLaunchKernelGGL(pack_kernel, dim3(512), dim3(64), 0, stream, hw, packed);
    hipLaunchKernelGGL(main_kernel, dim3(M / (16 * TPW)), dim3(256), 0, stream,
                       target, mask, packed, bias, out);
}